// Round 7
// baseline (38.019 us; speedup 1.0000x reference)
//
#include <hip/hip_runtime.h>

// 3x3 median filter, stride 1, reflect padding ("same"), NCHW fp32.
// Input: 32 x 3 x 512 x 512 fp32. Output: same shape.
//
// Rolling-window kernel: each wave owns an 8-row x 512-col stripe and walks
// down it keeping a 3-row window in registers. Per output row: 2 float4
// loads (ONE new input row), 2 shfl edge taps, ~54 VALU, 2 float4 stores.
//   - read amplification drops 3.0x -> 1.25x (10 rows loaded / 8 produced)
//   - next-row load issued 2 iterations ahead -> ~300 cyc latency hiding
//     per wave on top of cross-wave TLP
//   - separable median-of-9: column sort3 (v_min3/v_med3/v_max3) then
//     med3(max3(lo), med3(mi), min3(hi)); horizontal taps via shfl
//     (a wave's 64 lanes cover exactly one 512-wide row), reflect at 0/63.
//   - XCD-aware block swizzle (1536 blocks % 8 == 0 -> bijective).

#define IMG_H 512
#define IMG_W 512
#define NXCD 8
#define ROWS 8   // output rows per wave

__device__ __forceinline__ float min3f(float a, float b, float c) {
    return fminf(fminf(a, b), c);
}
__device__ __forceinline__ float max3f(float a, float b, float c) {
    return fmaxf(fmaxf(a, b), c);
}
__device__ __forceinline__ float med3f(float a, float b, float c) {
    return __builtin_amdgcn_fmed3f(a, b, c);   // v_med3_f32
}

__global__ __launch_bounds__(256) void median3x3_kernel(
        const float* __restrict__ in, float* __restrict__ out,
        int nplanes, int blocks_per_xcd) {
    // XCD swizzle: blocks with equal (blockIdx.x % 8) run on the same XCD.
    int bid = (int)blockIdx.x;
    int sbid = (bid & (NXCD - 1)) * blocks_per_xcd + (bid >> 3);

    const int lane = threadIdx.x & 63;
    const int stripe = sbid * 4 + (threadIdx.x >> 6);   // 8-row stripe
    const int plane = stripe >> 6;                      // 64 stripes/plane
    const int y0 = (stripe & 63) * ROWS;                // first out row
    const int x0 = lane * 8;                            // first out col
    if (plane >= nplanes) return;

    const size_t pbase = (size_t)plane * IMG_H * IMG_W;
    const float* bp = in + pbase;

    // circular window: 4 slots (3-row window + 1 in flight)
    float4 va[4], vb[4];
    float  Ls[4], Rs[4];

#define LOADROW(slot, yy)                                                    \
    do {                                                                     \
        const float* _r = bp + (size_t)(yy) * IMG_W + x0;                    \
        va[slot] = *reinterpret_cast<const float4*>(_r);                     \
        vb[slot] = *reinterpret_cast<const float4*>(_r + 4);                 \
    } while (0)

#define EDGES(slot)                                                          \
    do {                                                                     \
        float _l = __shfl_up(vb[slot].w, 1);                                 \
        float _r = __shfl_down(va[slot].x, 1);                               \
        Ls[slot] = (lane == 0)  ? va[slot].y : _l;  /* reflect(-1)=col 1 */  \
        Rs[slot] = (lane == 63) ? vb[slot].z : _r;  /* reflect(W)=col W-2 */ \
    } while (0)

    // prologue: rows y0-1 .. y0+2 into slots 0..3
    int ytop = (y0 == 0) ? 1 : y0 - 1;
    LOADROW(0, ytop);
    LOADROW(1, y0);
    LOADROW(2, y0 + 1);
    LOADROW(3, y0 + 2);
    EDGES(0); EDGES(1); EDGES(2);

    float* op = out + pbase + (size_t)y0 * IMG_W + x0;

#pragma unroll
    for (int t = 0; t < ROWS; ++t) {
        const int sA = t & 3, sB = (t + 1) & 3, sC = (t + 2) & 3;

        if (t >= 1) EDGES(sC);   // newly arrived bottom row

        const float A[10] = {Ls[sA], va[sA].x, va[sA].y, va[sA].z, va[sA].w,
                             vb[sA].x, vb[sA].y, vb[sA].z, vb[sA].w, Rs[sA]};
        const float B[10] = {Ls[sB], va[sB].x, va[sB].y, va[sB].z, va[sB].w,
                             vb[sB].x, vb[sB].y, vb[sB].z, vb[sB].w, Rs[sB]};
        const float C[10] = {Ls[sC], va[sC].x, va[sC].y, va[sC].z, va[sC].w,
                             vb[sC].x, vb[sC].y, vb[sC].z, vb[sC].w, Rs[sC]};

        float lo[10], mi[10], hi[10];
#pragma unroll
        for (int i = 0; i < 10; ++i) {
            lo[i] = min3f(A[i], B[i], C[i]);
            mi[i] = med3f(A[i], B[i], C[i]);
            hi[i] = max3f(A[i], B[i], C[i]);
        }
        float o[8];
#pragma unroll
        for (int i = 0; i < 8; ++i) {
            o[i] = med3f(max3f(lo[i], lo[i + 1], lo[i + 2]),
                         med3f(mi[i], mi[i + 1], mi[i + 2]),
                         min3f(hi[i], hi[i + 1], hi[i + 2]));
        }
        *reinterpret_cast<float4*>(op + (size_t)t * IMG_W)
            = make_float4(o[0], o[1], o[2], o[3]);
        *reinterpret_cast<float4*>(op + (size_t)t * IMG_W + 4)
            = make_float4(o[4], o[5], o[6], o[7]);

        // issue the load for row y0+t+3 (window bottom at iteration t+2)
        // into the slot that just went dead (sA). Rows y0+3 .. y0+ROWS.
        if (t < ROWS - 2) {
            int yn = y0 + t + 3;
            yn = (yn == IMG_H) ? IMG_H - 2 : yn;   // reflect at bottom edge
            LOADROW(sA, yn);
        }
    }
#undef LOADROW
#undef EDGES
}

extern "C" void kernel_launch(void* const* d_in, const int* in_sizes, int n_in,
                              void* d_out, int out_size, void* d_ws, size_t ws_size,
                              hipStream_t stream) {
    const float* x = (const float*)d_in[0];
    float* out = (float*)d_out;
    int nplanes = in_sizes[0] / (IMG_H * IMG_W);            // 32*3 = 96

    // one wave per 8-row stripe; 4 waves per block
    int stripes = nplanes * (IMG_H / ROWS);                 // 6,144
    int grid = stripes / 4;                                 // 1,536 blocks
    int blocks_per_xcd = grid / NXCD;                       // 192
    median3x3_kernel<<<grid, 256, 0, stream>>>(x, out, nplanes, blocks_per_xcd);
}

// Round 8
// 33.696 us; speedup vs baseline: 1.1283x; 1.1283x over previous
//
#include <hip/hip_runtime.h>

// 3x3 median filter, stride 1, reflect padding ("same"), NCHW fp32.
// Input: 32 x 3 x 512 x 512 fp32. Output: same shape.
//
// FINAL (reverted to round-6 best: 33.7us = ~95% of the 6.3 TB/s D2D
// ceiling on an ideal-traffic basis).
//
// Regime: latency-bound (VALUBusy ~12%, HBM ~35% during profiled cold
// passes). Winning recipe, established over R1-R7:
//   - MAXIMUM WAVE COUNT: one wave per output row -> 49,152 waves = 6x the
//     8,192 wave slots. Wave count beat every VMEM-density / read-reuse
//     optimization tried (R4/R7 with fewer waves regressed despite lower
//     logical traffic; L2/L3 absorbs the 3x vertical read amplification).
//   - per thread: 6 float4 loads (3 rows x 32B), 2 float4 stores, 8 outputs.
//   - horizontal edge taps via shfl (a wave's 64 lanes cover exactly one
//     512-wide row), reflect at lane 0/63. No uncoalesced scalar loads.
//   - separable median-of-9: column sort3 (v_min3/v_med3/v_max3), then
//     out = med3(max3(lo), med3(mi), min3(hi)) -> ~12 VALU ops/output.
//   - XCD-aware block swizzle: vertically-adjacent rows (sharing 2 input
//     rows) land on the same XCD's L2. 12288 blocks % 8 == 0 -> bijective.
//   - plain vector stores (nontemporal regressed: 4x store instrs, +17MB
//     WRITE_SIZE).

#define IMG_H 512
#define IMG_W 512
#define NXCD 8

__device__ __forceinline__ float min3f(float a, float b, float c) {
    return fminf(fminf(a, b), c);
}
__device__ __forceinline__ float max3f(float a, float b, float c) {
    return fmaxf(fmaxf(a, b), c);
}
__device__ __forceinline__ float med3f(float a, float b, float c) {
    return __builtin_amdgcn_fmed3f(a, b, c);   // v_med3_f32
}

__global__ __launch_bounds__(256) void median3x3_kernel(
        const float* __restrict__ in, float* __restrict__ out,
        int nplanes, int blocks_per_xcd) {
    // XCD swizzle: blocks with equal (blockIdx.x % 8) run on the same XCD;
    // give them contiguous row ranges for L2 row-overlap reuse.
    int bid = (int)blockIdx.x;
    int sbid = (bid & (NXCD - 1)) * blocks_per_xcd + (bid >> 3);

    const int lane = threadIdx.x & 63;
    const int row = sbid * 4 + (threadIdx.x >> 6);      // one output row
    const int plane = row >> 9;                         // / 512
    const int y = row & (IMG_H - 1);
    const int x0 = lane * 8;                            // first of 8 out cols
    if (plane >= nplanes) return;

    const size_t pbase = (size_t)plane * IMG_H * IMG_W;
    const float* bp = in + pbase;

    // reflect-pad row indices (pad=1): -1 -> 1, H -> H-2
    int ym = (y == 0)         ? 1         : y - 1;
    int yp = (y == IMG_H - 1) ? IMG_H - 2 : y + 1;
    const float* r0 = bp + (size_t)ym * IMG_W + x0;
    const float* r1 = bp + (size_t)y  * IMG_W + x0;
    const float* r2 = bp + (size_t)yp * IMG_W + x0;

    // 6 vector loads issued up front
    float4 a0 = *reinterpret_cast<const float4*>(r0);
    float4 a1 = *reinterpret_cast<const float4*>(r0 + 4);
    float4 b0 = *reinterpret_cast<const float4*>(r1);
    float4 b1 = *reinterpret_cast<const float4*>(r1 + 4);
    float4 c0 = *reinterpret_cast<const float4*>(r2);
    float4 c1 = *reinterpret_cast<const float4*>(r2 + 4);

    // horizontal edge taps from neighbor lanes (reflect at row ends)
    float aL = __shfl_up(a1.w, 1), aR = __shfl_down(a0.x, 1);
    float bL = __shfl_up(b1.w, 1), bR = __shfl_down(b0.x, 1);
    float cL = __shfl_up(c1.w, 1), cR = __shfl_down(c0.x, 1);
    if (lane == 0)  { aL = a0.y; bL = b0.y; cL = c0.y; }   // reflect(-1)=col 1
    if (lane == 63) { aR = a1.z; bR = b1.z; cR = c1.z; }   // reflect(512)=510

    const float A[10] = {aL, a0.x, a0.y, a0.z, a0.w, a1.x, a1.y, a1.z, a1.w, aR};
    const float B[10] = {bL, b0.x, b0.y, b0.z, b0.w, b1.x, b1.y, b1.z, b1.w, bR};
    const float C[10] = {cL, c0.x, c0.y, c0.z, c0.w, c1.x, c1.y, c1.z, c1.w, cR};

    float lo[10], mi[10], hi[10];
#pragma unroll
    for (int i = 0; i < 10; ++i) {
        lo[i] = min3f(A[i], B[i], C[i]);
        mi[i] = med3f(A[i], B[i], C[i]);
        hi[i] = max3f(A[i], B[i], C[i]);
    }
    float o[8];
#pragma unroll
    for (int i = 0; i < 8; ++i) {
        o[i] = med3f(max3f(lo[i], lo[i + 1], lo[i + 2]),
                     med3f(mi[i], mi[i + 1], mi[i + 2]),
                     min3f(hi[i], hi[i + 1], hi[i + 2]));
    }

    float* op = out + pbase + (size_t)y * IMG_W + x0;
    *reinterpret_cast<float4*>(op)     = make_float4(o[0], o[1], o[2], o[3]);
    *reinterpret_cast<float4*>(op + 4) = make_float4(o[4], o[5], o[6], o[7]);
}

extern "C" void kernel_launch(void* const* d_in, const int* in_sizes, int n_in,
                              void* d_out, int out_size, void* d_ws, size_t ws_size,
                              hipStream_t stream) {
    const float* x = (const float*)d_in[0];
    float* out = (float*)d_out;
    int nplanes = in_sizes[0] / (IMG_H * IMG_W);            // 32*3 = 96

    // one wave per output row; 4 waves per block
    int rows = nplanes * IMG_H;                             // 49,152
    int grid = rows / 4;                                    // 12,288 blocks
    int blocks_per_xcd = grid / NXCD;                       // 1,536
    median3x3_kernel<<<grid, 256, 0, stream>>>(x, out, nplanes, blocks_per_xcd);
}